// Round 6
// baseline (165.237 us; speedup 1.0000x reference)
//
#include <hip/hip_runtime.h>
#include <hip/hip_bf16.h>
#include <math.h>

// Problem constants: B=1024 batch, L=256 latent, H=512 hidden, T=16 types,
// N=128 nodes (num_nodes input is a fixed scalar = 128).
#define BB 1024
#define LL 256
#define HH 512
#define TT 16
#define NN 128

#define NODE_F4 (BB * NN * TT / 4)   // 524288 float4 (8 MB)
#define EDGE_F4 (BB * NN * NN / 4)   // 4194304 float4 (64 MB)

typedef short bf16x8 __attribute__((ext_vector_type(8)));   // 8 bf16 = 4 VGPRs
typedef float f32x4  __attribute__((ext_vector_type(4)));   // MFMA C/D + NT stores

static __device__ __forceinline__ short bfbits(float f) {
    __hip_bfloat16 h = __float2bfloat16(f);
    return *reinterpret_cast<short*>(&h);
}

// h LDS layout: 16 rows x 512 bf16 = 16 x 1024 B. XOR-swizzle the 16B chunk
// index with (row&7): A-frag reads (64 lanes, 16 distinct rows, 16B each at
// the same k-offset) would otherwise be an 8-way bank conflict (1024B row
// stride); swizzled -> 2-way (free, m136).
static __device__ __forceinline__ int h_addr(int row, int col) {
    return (row << 10) + ((((col >> 3) ^ (row & 7)) << 4)) + ((col & 7) << 1);
}

// ---------------------------------------------------------------------------
// K_PREP — weights-only prologue:
//   [0,128)   WzT[n][k]   = bf16(Wz[k][n])                (512x256, 32x32 tiles)
//   [128,384) WsumT[n][k] = bf16(We1[k][n]+We1[k+512][n]) (512x512 tiles)
//   [384,416) WnT[t][k]   = bf16(Wn[k][t])               (16x512, tiny)
//   [416]     p_acc zero (1024 f32) + grp_cnt zero (64 i32)
__device__ __forceinline__ void transpose_tile(const float* __restrict__ in,
                                               __hip_bfloat16* __restrict__ out,
                                               int k0, int n0, int Kdim, bool fold,
                                               __hip_bfloat16 (*tile)[34]) {
    const int tx = threadIdx.x & 31;
    const int ty = threadIdx.x >> 5;          // 0..7
    #pragma unroll
    for (int r = ty; r < 32; r += 8) {
        float v = in[(k0 + r) * HH + n0 + tx];        // row stride is 512 both uses
        if (fold) v += in[(k0 + r + HH) * HH + n0 + tx];
        tile[r][tx] = __float2bfloat16(v);
    }
    __syncthreads();
    #pragma unroll
    for (int r = ty; r < 32; r += 8) {
        out[(n0 + r) * Kdim + k0 + tx] = tile[tx][r];
    }
}

__global__ __launch_bounds__(256) void k_prep(const float* __restrict__ Wz,
                                              const float* __restrict__ We1,
                                              const float* __restrict__ Wn,
                                              __hip_bfloat16* __restrict__ WzT,
                                              __hip_bfloat16* __restrict__ WsumT,
                                              __hip_bfloat16* __restrict__ WnT,
                                              float* __restrict__ p_acc,
                                              int* __restrict__ grp_cnt) {
    __shared__ __hip_bfloat16 tile[32][34];   // +2 pad: conflict-free col reads
    const int bid = blockIdx.x;
    const int tid = threadIdx.x;
    if (bid < 128) {                          // 8 k-tiles x 16 n-tiles
        transpose_tile(Wz, WzT, (bid >> 4) * 32, (bid & 15) * 32, LL, false, tile);
    } else if (bid < 384) {                   // 16 k-tiles x 16 n-tiles
        const int t = bid - 128;
        transpose_tile(We1, WsumT, (t >> 4) * 32, (t & 15) * 32, HH, true, tile);
    } else if (bid < 416) {
        const int u = (bid - 384) * 256 + tid;   // 0..8191
        WnT[u] = __float2bfloat16(Wn[(u & 511) * TT + (u >> 9)]);
    } else {
        if (tid < 256) ((float4*)p_acc)[tid] = make_float4(0.f, 0.f, 0.f, 0.f);
        if (tid < 16)  ((int4*)grp_cnt)[tid] = make_int4(0, 0, 0, 0);
    }
}

// ---------------------------------------------------------------------------
// K_MAIN — 256 blocks x 512 threads, cooperative launch (co-residency
// guaranteed; we never call grid.sync — only a 4-block group barrier via
// device-scope atomics). Block (g = bid>>2, q = bid&3) shares batch rows
// r0 = g*16 with its 3 siblings:
//   A1: h[16x512] = relu(z @ Wz + bz) -> bf16 LDS (dup x4 per group; WzT is
//       L2-resident per XCD so the re-stream is cheap).
//   A2: node head: h @ WnT^T + bn, K split over 8 waves, LDS-reduced.
//   A3: p-head QUARTER (128 KB of WsumT per block — R5 showed the full-head
//       512 KB/block stream is the regression): wave w covers col-tile
//       nt = q*8+w; relu * We2, 16-lane butterfly -> atomicAdd p_acc.
//   sig: release-increment grp_cnt[g]; write node n-quarter (p-independent,
//        overlaps sibling lag); spin until grp_cnt[g]==4; acquire p.
//   W2: edge rows r0+q*4..+3 via nontemporal f32x4 stores.
__global__ __launch_bounds__(512) void k_main(const float* __restrict__ z,
                                              const __hip_bfloat16* __restrict__ WzT,
                                              const __hip_bfloat16* __restrict__ WsumT,
                                              const __hip_bfloat16* __restrict__ WnT,
                                              const float* __restrict__ bz,
                                              const float* __restrict__ be1,
                                              const float* __restrict__ We2,
                                              const float* __restrict__ bn,
                                              const float* __restrict__ be2,
                                              float* __restrict__ p_acc,
                                              int* __restrict__ grp_cnt,
                                              f32x4* __restrict__ out) {
    __shared__ char  hbuf[16384];             // h, swizzled (h_addr)
    __shared__ f32x4 nod_lds[8][64];          // node-head K-partials (8 KB)
    __shared__ float pw_lds[8][16];           // p-head wave partials
    __shared__ float nodef[16][16];           // reduced node vals [row][t]
    __shared__ float pfin[4];                 // sigmoid(p) for this block's rows

    const int tid  = threadIdx.x;
    const int w    = tid >> 6;                // wave 0..7
    const int lane = tid & 63;
    const int l16  = lane & 15, quad = lane >> 4;
    const int g = blockIdx.x >> 2, q = blockIdx.x & 3;
    const int r0 = g << 4;                    // this group's batch rows

    // ---- A1: h = relu(z @ Wz + bz) -> LDS (full 512 cols, dup x4) ----
    {
        bf16x8 afr[8];
        const float4* zf = (const float4*)(z + (r0 + l16) * LL);
        #pragma unroll
        for (int kt = 0; kt < 8; ++kt) {
            float4 v0 = zf[quad * 2 + kt * 8];
            float4 v1 = zf[quad * 2 + kt * 8 + 1];
            bf16x8 a;
            a[0] = bfbits(v0.x); a[1] = bfbits(v0.y); a[2] = bfbits(v0.z); a[3] = bfbits(v0.w);
            a[4] = bfbits(v1.x); a[5] = bfbits(v1.y); a[6] = bfbits(v1.z); a[7] = bfbits(v1.w);
            afr[kt] = a;
        }
        #pragma unroll
        for (int i = 0; i < 4; ++i) {         // wave w owns h cols [w*64,w*64+64)
            const int nt = (w << 2) + i;
            const short* Bp = (const short*)WzT + (nt * 16 + l16) * LL + quad * 8;
            f32x4 acc = {0.f, 0.f, 0.f, 0.f};
            #pragma unroll
            for (int kt = 0; kt < 8; ++kt) {
                bf16x8 b = *(const bf16x8*)(Bp + kt * 32);
                acc = __builtin_amdgcn_mfma_f32_16x16x32_bf16(afr[kt], b, acc, 0, 0, 0);
            }
            const int col = nt * 16 + l16;
            const float bb = bz[col];
            #pragma unroll
            for (int r = 0; r < 4; ++r) {     // C/D: row=quad*4+r, col=l16 (m89)
                float hv = fmaxf(acc[r] + bb, 0.f);
                *(short*)(hbuf + h_addr(quad * 4 + r, col)) = bfbits(hv);
            }
        }
    }
    __syncthreads();

    // ---- A2: node-head K-partials (K split over 8 waves) ----
    {
        f32x4 acc = {0.f, 0.f, 0.f, 0.f};
        const short* Bp = (const short*)WnT + l16 * HH + quad * 8;
        #pragma unroll
        for (int kk = 0; kk < 2; ++kk) {
            const int kt = w * 2 + kk;
            bf16x8 a = *(const bf16x8*)(hbuf + h_addr(l16, quad * 8 + kt * 32));
            bf16x8 b = *(const bf16x8*)(Bp + kt * 32);
            acc = __builtin_amdgcn_mfma_f32_16x16x32_bf16(a, b, acc, 0, 0, 0);
        }
        nod_lds[w][lane] = acc;
    }

    // ---- A3: p-head quarter (wave w -> e1 col-tile nt = q*8 + w) ----
    {
        const int nt = q * 8 + w;
        const short* Bp = (const short*)WsumT + (nt * 16 + l16) * HH + quad * 8;
        f32x4 acc = {0.f, 0.f, 0.f, 0.f};
        #pragma unroll
        for (int kt = 0; kt < 16; ++kt) {
            bf16x8 a = *(const bf16x8*)(hbuf + h_addr(l16, quad * 8 + kt * 32));
            bf16x8 b = *(const bf16x8*)(Bp + kt * 32);
            acc = __builtin_amdgcn_mfma_f32_16x16x32_bf16(a, b, acc, 0, 0, 0);
        }
        const int col = nt * 16 + l16;
        const float bb = be1[col], w2 = We2[col];
        float sr[4];
        #pragma unroll
        for (int r = 0; r < 4; ++r) sr[r] = fmaxf(acc[r] + bb, 0.f) * w2;
        #pragma unroll
        for (int off = 1; off < 16; off <<= 1) {  // sum over the 16 col-lanes
            #pragma unroll
            for (int r = 0; r < 4; ++r) sr[r] += __shfl_xor(sr[r], off);
        }
        if (l16 == 0) {
            #pragma unroll
            for (int r = 0; r < 4; ++r) pw_lds[w][quad * 4 + r] = sr[r];
        }
    }
    __syncthreads();

    // ---- block-level reductions ----
    if (w == 0) {                             // node finalize -> nodef LDS
        f32x4 s = nod_lds[0][lane];
        #pragma unroll
        for (int ww = 1; ww < 8; ++ww) {
            f32x4 t = nod_lds[ww][lane];
            s[0] += t[0]; s[1] += t[1]; s[2] += t[2]; s[3] += t[3];
        }
        const float bb = bn[l16];
        #pragma unroll
        for (int r = 0; r < 4; ++r)
            nodef[quad * 4 + r][l16] = s[r] + bb;
    }
    if (w == 1 && lane < 16) {                // p quarter-partial -> global
        float t = 0.f;
        #pragma unroll
        for (int ww = 0; ww < 8; ++ww) t += pw_lds[ww][lane];
        atomicAdd(p_acc + r0 + lane, t);      // device-scope (m20)
        __threadfence();                      // make adds visible pre-signal
    }
    __syncthreads();

    // ---- signal group arrival (release), then p-independent node write ----
    if (tid == 0)
        __hip_atomic_fetch_add(grp_cnt + g, 1, __ATOMIC_RELEASE,
                               __HIP_MEMORY_SCOPE_AGENT);

    // node write: this block covers n in [q*32, q*32+32):
    // region = 16 rows x 32 n x 4 f4 = 2048 f4 -> 4 f4 per thread.
    {
        const f32x4* nf4 = (const f32x4*)nodef;
        #pragma unroll
        for (int i = 0; i < 4; ++i) {
            const int idx = i * 512 + tid;    // 0..2047
            const int bl  = idx >> 7;         // local row 0..15 (128 f4/row)
            const int rem = idx & 127;
            const int nl  = rem >> 2;         // n within quarter 0..31
            const int t4  = rem & 3;
            __builtin_nontemporal_store(nf4[bl * 4 + t4],
                out + (r0 + bl) * 512 + (q * 32 + nl) * 4 + t4);
        }
    }

    // ---- group barrier: wait for all 4 sibling blocks' p contributions ----
    if (tid == 0) {
        while (__hip_atomic_load(grp_cnt + g, __ATOMIC_ACQUIRE,
                                 __HIP_MEMORY_SCOPE_AGENT) < 4) { }
    }
    __syncthreads();
    if (tid < 4) {                            // this block's 4 edge rows
        float t = __hip_atomic_load(p_acc + r0 + (q << 2) + tid,
                                    __ATOMIC_RELAXED, __HIP_MEMORY_SCOPE_AGENT);
        pfin[tid] = 1.f / (1.f + expf(-(t + be2[0])));
    }
    __syncthreads();

    // ---- W2: edge write, rows b = r0 + q*4 .. +3 (256 KB per block) ----
    {
        f32x4* oedge = out + NODE_F4;
        #pragma unroll
        for (int i = 0; i < 4; ++i) {
            const int b = r0 + (q << 2) + i;
            const float pv = pfin[i];
            #pragma unroll
            for (int it = 0; it < 8; ++it) {  // 4096 f4 per row, 8 per thread
                const int e  = it * 512 + tid;
                const int ii = e >> 5;
                const int j0 = (e & 31) << 2;
                f32x4 v;
                v[0] = (j0 + 0 < ii) ? pv : 0.f;
                v[1] = (j0 + 1 < ii) ? pv : 0.f;
                v[2] = (j0 + 2 < ii) ? pv : 0.f;
                v[3] = (j0 + 3 < ii) ? pv : 0.f;
                __builtin_nontemporal_store(v, oedge + b * 4096 + e);
            }
        }
    }
}

// ---------------------------------------------------------------------------
extern "C" void kernel_launch(void* const* d_in, const int* in_sizes, int n_in,
                              void* d_out, int out_size, void* d_ws, size_t ws_size,
                              hipStream_t stream) {
    const float* z    = (const float*)d_in[0];
    // d_in[1] = num_nodes (int scalar) — fixed at 128, hard-coded as NN.
    const float* Wz   = (const float*)d_in[2];
    const float* bz   = (const float*)d_in[3];
    const float* Wn   = (const float*)d_in[4];
    const float* bn   = (const float*)d_in[5];
    const float* We1  = (const float*)d_in[6];
    const float* be1  = (const float*)d_in[7];
    const float* We2  = (const float*)d_in[8];
    const float* be2  = (const float*)d_in[9];
    float* out = (float*)d_out;

    // Workspace (bytes, 256B-aligned):
    char* base = (char*)d_ws;
    __hip_bfloat16* WzT    = (__hip_bfloat16*)(base);                 // 256 KB [512][256]
    __hip_bfloat16* WsumT  = (__hip_bfloat16*)(base +  256 * 1024);   // 512 KB [512][512]
    __hip_bfloat16* WnT    = (__hip_bfloat16*)(base +  768 * 1024);   //  16 KB [16][512]
    float*          p_acc  = (float*)(base + 784 * 1024);             //   4 KB
    int*            grpcnt = (int*)(base + 788 * 1024);               // 256 B

    // 1) weight transposes + p_acc/grp_cnt zero
    k_prep<<<417, 256, 0, stream>>>(Wz, We1, Wn, WzT, WsumT, WnT, p_acc, grpcnt);

    // 2) everything else: cooperative launch guarantees all 256 blocks are
    //    co-resident (1/CU); only 4-block group barriers via device atomics.
    {
        f32x4* outv = (f32x4*)out;
        void* args[] = { (void*)&z, (void*)&WzT, (void*)&WsumT, (void*)&WnT,
                         (void*)&bz, (void*)&be1, (void*)&We2, (void*)&bn,
                         (void*)&be2, (void*)&p_acc, (void*)&grpcnt,
                         (void*)&outv };
        hipLaunchCooperativeKernel((const void*)k_main, dim3(256), dim3(512),
                                   args, 0, stream);
    }

    (void)in_sizes; (void)n_in; (void)out_size; (void)ws_size;
}

// Round 7
// 125.370 us; speedup vs baseline: 1.3180x; 1.3180x over previous
//
#include <hip/hip_runtime.h>
#include <hip/hip_bf16.h>
#include <math.h>

// Problem constants: B=1024 batch, L=256 latent, H=512 hidden, T=16 types,
// N=128 nodes (num_nodes input is a fixed scalar = 128).
#define BB 1024
#define LL 256
#define HH 512
#define TT 16
#define NN 128

#define NODE_F4 (BB * NN * TT / 4)   // 524288 float4 (8 MB)
#define EDGE_F4 (BB * NN * NN / 4)   // 4194304 float4 (64 MB)

typedef short bf16x8 __attribute__((ext_vector_type(8)));   // 8 bf16 = 4 VGPRs
typedef float f32x4  __attribute__((ext_vector_type(4)));   // MFMA C/D + NT stores

static __device__ __forceinline__ short bfbits(float f) {
    __hip_bfloat16 h = __float2bfloat16(f);
    return *reinterpret_cast<short*>(&h);
}

// h LDS layout: 16 rows x 512 bf16 = 16 x 1024 B. XOR-swizzle the 16B chunk
// index with (row&7): A-frag reads (64 lanes, 16 distinct rows, 16B each at
// the same k-offset) would otherwise be an 8-way bank conflict (1024B row
// stride); swizzled -> 2-way (free, m136).
static __device__ __forceinline__ int h_addr(int row, int col) {
    return (row << 10) + ((((col >> 3) ^ (row & 7)) << 4)) + ((col & 7) << 1);
}

// ---------------------------------------------------------------------------
// K_PREP — weights-only prologue:
//   [0,128)   WzT[n][k]   = bf16(Wz[k][n])                (512x256, 32x32 tiles)
//   [128,384) WsumT[n][k] = bf16(We1[k][n]+We1[k+512][n]) (512x512 tiles)
//   [384,416) WnT[t][k]   = bf16(Wn[k][t])               (16x512, tiny)
//   [416]     p_acc zero (1024 floats)
__device__ __forceinline__ void transpose_tile(const float* __restrict__ in,
                                               __hip_bfloat16* __restrict__ out,
                                               int k0, int n0, int Kdim, bool fold,
                                               __hip_bfloat16 (*tile)[34]) {
    const int tx = threadIdx.x & 31;
    const int ty = threadIdx.x >> 5;          // 0..7
    #pragma unroll
    for (int r = ty; r < 32; r += 8) {
        float v = in[(k0 + r) * HH + n0 + tx];        // row stride is 512 both uses
        if (fold) v += in[(k0 + r + HH) * HH + n0 + tx];
        tile[r][tx] = __float2bfloat16(v);
    }
    __syncthreads();
    #pragma unroll
    for (int r = ty; r < 32; r += 8) {
        out[(n0 + r) * Kdim + k0 + tx] = tile[tx][r];
    }
}

__global__ __launch_bounds__(256) void k_prep(const float* __restrict__ Wz,
                                              const float* __restrict__ We1,
                                              const float* __restrict__ Wn,
                                              __hip_bfloat16* __restrict__ WzT,
                                              __hip_bfloat16* __restrict__ WsumT,
                                              __hip_bfloat16* __restrict__ WnT,
                                              float* __restrict__ p_acc) {
    __shared__ __hip_bfloat16 tile[32][34];   // +2 pad: conflict-free col reads
    const int bid = blockIdx.x;
    const int tid = threadIdx.x;
    if (bid < 128) {                          // 8 k-tiles x 16 n-tiles
        transpose_tile(Wz, WzT, (bid >> 4) * 32, (bid & 15) * 32, LL, false, tile);
    } else if (bid < 384) {                   // 16 k-tiles x 16 n-tiles
        const int t = bid - 128;
        transpose_tile(We1, WsumT, (t >> 4) * 32, (t & 15) * 32, HH, true, tile);
    } else if (bid < 416) {
        const int u = (bid - 384) * 256 + tid;   // 0..8191
        WnT[u] = __float2bfloat16(Wn[(u & 511) * TT + (u >> 9)]);
    } else if (tid < 256) {
        ((float4*)p_acc)[tid] = make_float4(0.f, 0.f, 0.f, 0.f);
    }
}

// ---------------------------------------------------------------------------
// K_FUSED — 256 blocks x 512 threads (1 block/CU). Block (g = bid>>2,
// q = bid&3) owns batch rows r0 = g*16 (h duplicated over the 4 q-blocks;
// WzT is L2-resident so duplication is cheap — R5 showed the full-p-head
// alternative's 512KB/block WsumT stream is worse):
//   A1: h[16x512] = relu(z @ Wz + bz) -> bf16 LDS (z converted in-register)
//   A2: node head: h @ WnT^T + bn, K split over 8 waves, LDS-reduced, then
//       this block NT-writes node_logits for its n-quarter straight to out.
//   A3: p-head quarter: wave w covers e1 col-tile nt = q*8+w; relu * We2,
//       butterfly over 16 col-lanes, block partial -> atomicAdd p_acc.
__global__ __launch_bounds__(512) void k_fused(const float* __restrict__ z,
                                               const __hip_bfloat16* __restrict__ WzT,
                                               const __hip_bfloat16* __restrict__ WsumT,
                                               const __hip_bfloat16* __restrict__ WnT,
                                               const float* __restrict__ bz,
                                               const float* __restrict__ be1,
                                               const float* __restrict__ We2,
                                               const float* __restrict__ bn,
                                               float* __restrict__ p_acc,
                                               f32x4* __restrict__ out) {
    __shared__ char  hbuf[16384];             // h, swizzled (h_addr)
    __shared__ f32x4 nod_lds[8][64];          // node-head K-partials (8 KB)
    __shared__ float pw_lds[8][16];           // p-head wave partials
    __shared__ float nodef[16][16];           // reduced node vals [row][t]

    const int tid  = threadIdx.x;
    const int w    = tid >> 6;                // wave 0..7
    const int lane = tid & 63;
    const int l16  = lane & 15, quad = lane >> 4;
    const int g = blockIdx.x >> 2, q = blockIdx.x & 3;
    const int r0 = g << 4;                    // this group's batch rows

    // ---- A1: h = relu(z @ Wz + bz) -> LDS (full 512 cols, dup x4) ----
    {
        bf16x8 afr[8];
        const float4* zf = (const float4*)(z + (r0 + l16) * LL);
        #pragma unroll
        for (int kt = 0; kt < 8; ++kt) {
            float4 v0 = zf[quad * 2 + kt * 8];
            float4 v1 = zf[quad * 2 + kt * 8 + 1];
            bf16x8 a;
            a[0] = bfbits(v0.x); a[1] = bfbits(v0.y); a[2] = bfbits(v0.z); a[3] = bfbits(v0.w);
            a[4] = bfbits(v1.x); a[5] = bfbits(v1.y); a[6] = bfbits(v1.z); a[7] = bfbits(v1.w);
            afr[kt] = a;
        }
        #pragma unroll
        for (int i = 0; i < 4; ++i) {         // wave w owns h cols [w*64,w*64+64)
            const int nt = (w << 2) + i;
            const short* Bp = (const short*)WzT + (nt * 16 + l16) * LL + quad * 8;
            f32x4 acc = {0.f, 0.f, 0.f, 0.f};
            #pragma unroll
            for (int kt = 0; kt < 8; ++kt) {
                bf16x8 b = *(const bf16x8*)(Bp + kt * 32);
                acc = __builtin_amdgcn_mfma_f32_16x16x32_bf16(afr[kt], b, acc, 0, 0, 0);
            }
            const int col = nt * 16 + l16;
            const float bb = bz[col];
            #pragma unroll
            for (int r = 0; r < 4; ++r) {     // C/D: row=quad*4+r, col=l16 (m89)
                float hv = fmaxf(acc[r] + bb, 0.f);
                *(short*)(hbuf + h_addr(quad * 4 + r, col)) = bfbits(hv);
            }
        }
    }
    __syncthreads();

    // ---- A2: node-head K-partials (K split over 8 waves) ----
    {
        f32x4 acc = {0.f, 0.f, 0.f, 0.f};
        const short* Bp = (const short*)WnT + l16 * HH + quad * 8;
        #pragma unroll
        for (int kk = 0; kk < 2; ++kk) {
            const int kt = w * 2 + kk;
            bf16x8 a = *(const bf16x8*)(hbuf + h_addr(l16, quad * 8 + kt * 32));
            bf16x8 b = *(const bf16x8*)(Bp + kt * 32);
            acc = __builtin_amdgcn_mfma_f32_16x16x32_bf16(a, b, acc, 0, 0, 0);
        }
        nod_lds[w][lane] = acc;
    }

    // ---- A3: p-head quarter (wave w -> e1 col-tile nt = q*8 + w) ----
    {
        const int nt = q * 8 + w;
        const short* Bp = (const short*)WsumT + (nt * 16 + l16) * HH + quad * 8;
        f32x4 acc = {0.f, 0.f, 0.f, 0.f};
        #pragma unroll
        for (int kt = 0; kt < 16; ++kt) {
            bf16x8 a = *(const bf16x8*)(hbuf + h_addr(l16, quad * 8 + kt * 32));
            bf16x8 b = *(const bf16x8*)(Bp + kt * 32);
            acc = __builtin_amdgcn_mfma_f32_16x16x32_bf16(a, b, acc, 0, 0, 0);
        }
        const int col = nt * 16 + l16;
        const float bb = be1[col], w2 = We2[col];
        float sr[4];
        #pragma unroll
        for (int r = 0; r < 4; ++r) sr[r] = fmaxf(acc[r] + bb, 0.f) * w2;
        #pragma unroll
        for (int off = 1; off < 16; off <<= 1) {  // sum over the 16 col-lanes
            #pragma unroll
            for (int r = 0; r < 4; ++r) sr[r] += __shfl_xor(sr[r], off);
        }
        if (l16 == 0) {
            #pragma unroll
            for (int r = 0; r < 4; ++r) pw_lds[w][quad * 4 + r] = sr[r];
        }
    }
    __syncthreads();

    // ---- block-level reductions ----
    if (w == 0) {                             // node finalize -> nodef LDS
        f32x4 s = nod_lds[0][lane];
        #pragma unroll
        for (int ww = 1; ww < 8; ++ww) {
            f32x4 t = nod_lds[ww][lane];
            s[0] += t[0]; s[1] += t[1]; s[2] += t[2]; s[3] += t[3];
        }
        const float bb = bn[l16];
        #pragma unroll
        for (int r = 0; r < 4; ++r)
            nodef[quad * 4 + r][l16] = s[r] + bb;
    }
    if (w == 1 && lane < 16) {                // p quarter-partial -> global
        float t = 0.f;
        #pragma unroll
        for (int ww = 0; ww < 8; ++ww) t += pw_lds[ww][lane];
        atomicAdd(p_acc + r0 + lane, t);      // device-scope (m20)
    }
    __syncthreads();

    // ---- node NT write: this block covers n in [q*32, q*32+32) ----
    // region = 16 rows x 32 n x 4 f4 = 2048 f4 -> 4 f4 per thread.
    {
        const f32x4* nf4 = (const f32x4*)nodef;
        #pragma unroll
        for (int i = 0; i < 4; ++i) {
            const int idx = i * 512 + tid;    // 0..2047
            const int bl  = idx >> 7;         // local row 0..15 (128 f4/row)
            const int rem = idx & 127;
            const int nl  = rem >> 2;         // n within quarter 0..31
            const int t4  = rem & 3;
            __builtin_nontemporal_store(nf4[bl * 4 + t4],
                out + (r0 + bl) * 512 + (q * 32 + nl) * 4 + t4);
        }
    }
}

// ---------------------------------------------------------------------------
// K_EDGE: the 64 MiB edge broadcast (the roofline term, ~10.5 us floor).
// One block per batch row: p_acc[b] is a single broadcast load, sigmoid
// computed once per thread, then 16 row-local fully-coalesced NT stores.
__global__ __launch_bounds__(256) void k_edge(const float* __restrict__ p_acc,
                                              const float* __restrict__ be2,
                                              f32x4* __restrict__ oedge) {
    const int b   = blockIdx.x;               // 0..1023
    const int tid = threadIdx.x;
    const float pv = 1.f / (1.f + expf(-(p_acc[b] + be2[0])));
    f32x4* row = oedge + b * 4096;            // 4096 f4 per row (64 KB)
    #pragma unroll
    for (int it = 0; it < 16; ++it) {
        const int f  = it * 256 + tid;        // f4 index in row
        const int i  = f >> 5;                // node i = f/32
        const int j0 = (f & 31) << 2;         // j of first element
        f32x4 v;
        v[0] = (j0 + 0 < i) ? pv : 0.f;
        v[1] = (j0 + 1 < i) ? pv : 0.f;
        v[2] = (j0 + 2 < i) ? pv : 0.f;
        v[3] = (j0 + 3 < i) ? pv : 0.f;
        __builtin_nontemporal_store(v, row + f);
    }
}

// ---------------------------------------------------------------------------
extern "C" void kernel_launch(void* const* d_in, const int* in_sizes, int n_in,
                              void* d_out, int out_size, void* d_ws, size_t ws_size,
                              hipStream_t stream) {
    const float* z    = (const float*)d_in[0];
    // d_in[1] = num_nodes (int scalar) — fixed at 128, hard-coded as NN.
    const float* Wz   = (const float*)d_in[2];
    const float* bz   = (const float*)d_in[3];
    const float* Wn   = (const float*)d_in[4];
    const float* bn   = (const float*)d_in[5];
    const float* We1  = (const float*)d_in[6];
    const float* be1  = (const float*)d_in[7];
    const float* We2  = (const float*)d_in[8];
    const float* be2  = (const float*)d_in[9];
    float* out = (float*)d_out;

    // Workspace (bytes, 256B-aligned):
    char* base = (char*)d_ws;
    __hip_bfloat16* WzT    = (__hip_bfloat16*)(base);                 // 256 KB [512][256]
    __hip_bfloat16* WsumT  = (__hip_bfloat16*)(base +  256 * 1024);   // 512 KB [512][512]
    __hip_bfloat16* WnT    = (__hip_bfloat16*)(base +  768 * 1024);   //  16 KB [16][512]
    float*          p_acc  = (float*)(base + 784 * 1024);             //   4 KB

    // 1) weight transposes + p_acc zero
    k_prep<<<417, 256, 0, stream>>>(Wz, We1, Wn, WzT, WsumT, WnT, p_acc);

    // 2) fused compute at full occupancy (1 block/CU); NT-writes node region,
    //    p quarter-partials -> p_acc atomics
    k_fused<<<256, 512, 0, stream>>>(z, WzT, WsumT, WnT,
                                     bz, be1, We2, bn, p_acc, (f32x4*)out);

    // 3) 64 MiB edge broadcast, one block per batch row
    k_edge<<<BB, 256, 0, stream>>>(p_acc, be2, (f32x4*)out + NODE_F4);

    (void)in_sizes; (void)n_in; (void)out_size; (void)ws_size;
}